// Round 3
// baseline (1142.729 us; speedup 1.0000x reference)
//
#include <hip/hip_runtime.h>

typedef unsigned int uint_t;

#define SEQ 15
#define BATCH 32
#define NNODES 5000
#define NEDGES 80000
#define INFEAT 16
#define HID 512
#define G3 1536   // 3*HID
#define GRU_BLOCKS 256
#define BAR_INTS (32 * (2 * GRU_BLOCKS))   // 256 slot lines + 256 flag lines

// split-K GEMM config
#define KSPLIT 9
#define KCHUNK 576          // 9*576 = 5184 >= 5000; last chunk = 392
#define MROWS 480           // SEQ*BATCH
#define LDSP 68             // padded LDS row stride (64 + 4): 2-way banks (free)

// GRU GEMV config
#define NSLC 16             // k-slices (each thread covers 32 k, strided)
#define PPAD 36             // part row pad (multiple of 4; 2-way banks on write)

__device__ __forceinline__ float sigmoidf(float x){ return 1.0f / (1.0f + __expf(-x)); }

// ---------------- init ----------------
__global__ void k_init(int* counts, int* fill, int* bar,
                       float* h0a, float* h0b, float* h1a, float* h1b){
    int t = blockIdx.x * 256 + threadIdx.x;   // 0..16383
    if (t < NNODES){ counts[t] = 0; fill[t] = 0; }
    if (t < BAR_INTS) bar[t] = 0;
    h0a[t] = 0.f; h0b[t] = 0.f; h1a[t] = 0.f; h1b[t] = 0.f;
}

// ---------------- degree count (by target col) ----------------
__global__ void k_count(const int* ei, int* counts){
    int e = blockIdx.x * 256 + threadIdx.x;
    if (e < NEDGES) atomicAdd(&counts[ei[NEDGES + e]], 1);
}

__global__ void k_dinv(const int* counts, float* dinv){
    int n = blockIdx.x * 256 + threadIdx.x;
    if (n < NNODES) dinv[n] = rsqrtf(1.0f + (float)counts[n]);  // +1 self loop
}

// ---------------- exclusive scan of counts -> offs (single block) ----------------
__global__ void k_scan(const int* counts, int* offs){
    __shared__ int sdata[1024];
    int tid = threadIdx.x;
    int base = tid * 5;
    int loc[5]; int tot = 0;
    #pragma unroll
    for (int q = 0; q < 5; q++){
        int idx = base + q;
        int v = (idx < NNODES) ? counts[idx] : 0;
        loc[q] = tot; tot += v;
    }
    sdata[tid] = tot; __syncthreads();
    for (int off = 1; off < 1024; off <<= 1){
        int t = (tid >= off) ? sdata[tid - off] : 0;
        __syncthreads();
        sdata[tid] += t;
        __syncthreads();
    }
    int excl = sdata[tid] - tot;
    #pragma unroll
    for (int q = 0; q < 5; q++){
        int idx = base + q;
        if (idx < NNODES) offs[idx] = excl + loc[q];
    }
    if (tid == 1023) offs[NNODES] = sdata[1023];
}

// ---------------- CSR fill: bucket sources by target ----------------
__global__ void k_fill(const int* ei, const int* offs, int* fill, int* csr){
    int e = blockIdx.x * 256 + threadIdx.x;
    if (e < NEDGES){
        int c = ei[NEDGES + e];
        int p = offs[c] + atomicAdd(&fill[c], 1);
        csr[p] = ei[e];
    }
}

// ---------------- conv1 linear: h1s[s,b,n,{0,1}] = dinv[n] * (x[s,b,n,:] @ W1[s]) ----------------
__global__ void k_conv1(const float* x, const float* W1, const float* dinv, float* h1s){
    int n = blockIdx.x * 256 + threadIdx.x;
    int b = blockIdx.y, s = blockIdx.z;
    if (n >= NNODES) return;
    float w[32];
    #pragma unroll
    for (int q = 0; q < 32; q++) w[q] = W1[s * 32 + q];   // s uniform -> scalar loads
    size_t idx = ((size_t)(s * BATCH + b) * NNODES + n);
    const float4* xp = (const float4*)(x + idx * INFEAT);
    float4 u0 = xp[0], u1 = xp[1], u2 = xp[2], u3 = xp[3];
    float xs[16] = { u0.x,u0.y,u0.z,u0.w, u1.x,u1.y,u1.z,u1.w,
                     u2.x,u2.y,u2.z,u2.w, u3.x,u3.y,u3.z,u3.w };
    float a0 = 0.f, a1 = 0.f;
    #pragma unroll
    for (int f = 0; f < 16; f++){ a0 += xs[f] * w[2 * f]; a1 += xs[f] * w[2 * f + 1]; }
    float d = dinv[n];
    ((float2*)h1s)[idx] = make_float2(d * a0, d * a1);
}

// ------- aggregate1 + bias + relu + conv2 linear + pre-scale: h2s = dinv * (relu(dinv*agg + b1) @ W2) -------
__global__ void k_agg1(const float* h1s, const int* offs, const int* csr, const float* dinv,
                       const float* b1, const float* W2, float* h2s){
    int n = blockIdx.x * 256 + threadIdx.x;
    int b = blockIdx.y, s = blockIdx.z;
    if (n >= NNODES) return;
    size_t base = (size_t)(s * BATCH + b) * NNODES;
    const float2* hp = (const float2*)h1s + base;
    float2 self = hp[n];
    float a0 = self.x, a1 = self.y;
    int p1 = offs[n + 1];
    for (int p = offs[n]; p < p1; p++){
        float2 v = hp[csr[p]];
        a0 += v.x; a1 += v.y;
    }
    float d = dinv[n];
    float r0 = fmaxf(d * a0 + b1[s * 2 + 0], 0.f);
    float r1 = fmaxf(d * a1 + b1[s * 2 + 1], 0.f);
    float t2 = r0 * W2[s * 2 + 0] + r1 * W2[s * 2 + 1];
    h2s[base + n] = d * t2;
}

// ------- aggregate2 + bias + tanh -> g[s*32+b][n] -------
__global__ void k_agg2(const float* h2s, const int* offs, const int* csr, const float* dinv,
                       const float* b2, float* g){
    int n = blockIdx.x * 256 + threadIdx.x;
    int b = blockIdx.y, s = blockIdx.z;
    if (n >= NNODES) return;
    size_t base = (size_t)(s * BATCH + b) * NNODES;
    const float* hp = h2s + base;
    float a = hp[n];
    int p1 = offs[n + 1];
    for (int p = offs[n]; p < p1; p++) a += hp[csr[p]];
    g[base + n] = tanhf(dinv[n] * a + b2[s]);
}

// ------- split-K GEMM: part[z][480][1536] += A[480][kz] @ W[1536][kz]^T -------
__global__ __launch_bounds__(256) void k_gemm(const float* A, const float* W,
                                              float* part){
    __shared__ float As[16 * LDSP];
    __shared__ float Bs[16 * LDSP];
    int tid = threadIdx.x;
    int j0 = blockIdx.x * 64;   // N tile (1536/64 = 24)
    int m0 = blockIdx.y * 64;   // M tile (ceil(480/64) = 8)
    int kz = blockIdx.z;        // K split
    int kbeg = kz * KCHUNK;
    int kend = kbeg + KCHUNK; if (kend > 5000) kend = 5000;
    int tm = tid >> 4, tn = tid & 15;
    int lr = tid >> 2;           // 0..63
    int lk = (tid & 3) * 4;      // 0,4,8,12
    float acc[4][4];
    #pragma unroll
    for (int i = 0; i < 4; i++)
        #pragma unroll
        for (int j = 0; j < 4; j++) acc[i][j] = 0.f;

    for (int k0 = kbeg; k0 < kend; k0 += 16){
        int m = m0 + lr;
        float4 av = make_float4(0.f, 0.f, 0.f, 0.f);
        if (m < MROWS && (k0 + lk) < 5000)
            av = *(const float4*)&A[(size_t)m * 5000 + k0 + lk];
        As[(lk + 0) * LDSP + lr] = av.x; As[(lk + 1) * LDSP + lr] = av.y;
        As[(lk + 2) * LDSP + lr] = av.z; As[(lk + 3) * LDSP + lr] = av.w;
        int j = j0 + lr;
        float4 bv = make_float4(0.f, 0.f, 0.f, 0.f);
        if ((k0 + lk) < 5000)
            bv = *(const float4*)&W[(size_t)j * 5000 + k0 + lk];
        Bs[(lk + 0) * LDSP + lr] = bv.x; Bs[(lk + 1) * LDSP + lr] = bv.y;
        Bs[(lk + 2) * LDSP + lr] = bv.z; Bs[(lk + 3) * LDSP + lr] = bv.w;
        __syncthreads();
        #pragma unroll
        for (int k = 0; k < 16; k++){
            float4 a = *(float4*)&As[k * LDSP + tm * 4];
            float4 bb = *(float4*)&Bs[k * LDSP + tn * 4];
            acc[0][0] += a.x * bb.x; acc[0][1] += a.x * bb.y; acc[0][2] += a.x * bb.z; acc[0][3] += a.x * bb.w;
            acc[1][0] += a.y * bb.x; acc[1][1] += a.y * bb.y; acc[1][2] += a.y * bb.z; acc[1][3] += a.y * bb.w;
            acc[2][0] += a.z * bb.x; acc[2][1] += a.z * bb.y; acc[2][2] += a.z * bb.z; acc[2][3] += a.z * bb.w;
            acc[3][0] += a.w * bb.x; acc[3][1] += a.w * bb.y; acc[3][2] += a.w * bb.z; acc[3][3] += a.w * bb.w;
        }
        __syncthreads();
    }
    size_t zbase = (size_t)kz * MROWS * G3;
    #pragma unroll
    for (int i = 0; i < 4; i++){
        int m = m0 + tm * 4 + i;
        if (m < MROWS){
            #pragma unroll
            for (int j = 0; j < 4; j++){
                int col = j0 + tn * 4 + j;
                part[zbase + (size_t)m * G3 + col] = acc[i][j];
            }
        }
    }
}

// ------- reduce split-K partials + bias -> gi0 -------
__global__ __launch_bounds__(256) void k_gred(const float* part, const float* bias, float* C){
    int idx = blockIdx.x * 256 + threadIdx.x;   // 0 .. 480*1536-1
    float s = bias[idx % G3];
    float sum = 0.f;
    #pragma unroll
    for (int z = 0; z < KSPLIT; z++)
        sum += part[(size_t)z * MROWS * G3 + idx];
    C[idx] = sum + s;
}

// ------- contention-free grid barrier -----------------------------------------
__device__ __forceinline__ void grid_barrier(int* bar, int phase){
    __syncthreads();
    if (threadIdx.x == 0){
        __threadfence();   // release: drain this block's global writes
        __hip_atomic_store(&bar[32 * blockIdx.x], phase,
                           __ATOMIC_RELAXED, __HIP_MEMORY_SCOPE_AGENT);
    }
    if (blockIdx.x == 0 && threadIdx.x < 64){
        int lane = threadIdx.x;
        for (;;){
            int mn = 0x7fffffff;
            #pragma unroll
            for (int q = 0; q < 4; q++){
                int v = __hip_atomic_load(&bar[32 * (lane + 64 * q)],
                                          __ATOMIC_RELAXED, __HIP_MEMORY_SCOPE_AGENT);
                mn = min(mn, v);
            }
            if (__all(mn >= phase)) break;
            __builtin_amdgcn_s_sleep(4);
        }
        __threadfence();   // acquire observed slots; order before flag stores
        #pragma unroll
        for (int q = 0; q < 4; q++)
            __hip_atomic_store(&bar[32 * (GRU_BLOCKS + lane + 64 * q)], phase,
                               __ATOMIC_RELAXED, __HIP_MEMORY_SCOPE_AGENT);
    }
    if (threadIdx.x == 0){
        while (__hip_atomic_load(&bar[32 * (GRU_BLOCKS + blockIdx.x)],
                                 __ATOMIC_RELAXED, __HIP_MEMORY_SCOPE_AGENT) < phase)
            __builtin_amdgcn_s_sleep(4);
        __threadfence();   // acquire: invalidate stale cached h-state
    }
    __syncthreads();
}

// ------- per-group partial GEMV: NR rows x 32 k (strided) x 4 batches ---------
// R7: NR=6/3 (was 12/6 with a 2x-redundant (bq,ks) decomposition -- tids
// 128..255 duplicated tids 0..127 exactly). Halves FMAs + LDS reads, and
// drops live regs ~112 -> ~70: kills the scratch spill (WRITE_SIZE 40MB).
template<int NR>
__device__ __forceinline__ void gemv_part(const float* __restrict__ h,
                                          const float* __restrict__ wsm0,
                                          float* __restrict__ part0, int bq, int ks){
    float acc[NR][4];
    #pragma unroll
    for (int r = 0; r < NR; r++){ acc[r][0] = acc[r][1] = acc[r][2] = acc[r][3] = 0.f; }
    #pragma unroll
    for (int j = 0; j < 8; j++){
        int k = ks * 4 + j * 64;
        float4 hv0 = *(const float4*)&h[(k + 0) * 32 + 4 * bq];
        float4 hv1 = *(const float4*)&h[(k + 1) * 32 + 4 * bq];
        float4 hv2 = *(const float4*)&h[(k + 2) * 32 + 4 * bq];
        float4 hv3 = *(const float4*)&h[(k + 3) * 32 + 4 * bq];
        #pragma unroll
        for (int r = 0; r < NR; r++){
            float4 w = *(const float4*)&wsm0[r * HID + k];
            acc[r][0] += w.x * hv0.x + w.y * hv1.x + w.z * hv2.x + w.w * hv3.x;
            acc[r][1] += w.x * hv0.y + w.y * hv1.y + w.z * hv2.y + w.w * hv3.y;
            acc[r][2] += w.x * hv0.z + w.y * hv1.z + w.z * hv2.z + w.w * hv3.z;
            acc[r][3] += w.x * hv0.w + w.y * hv1.w + w.z * hv2.w + w.w * hv3.w;
        }
    }
    #pragma unroll
    for (int r = 0; r < NR; r++)
        *(float4*)&part0[(r * NSLC + ks) * PPAD + 4 * bq] =
            make_float4(acc[r][0], acc[r][1], acc[r][2], acc[r][3]);
}

// ------- persistent 2-layer GRU, layer-pipelined: ONE barrier per step --------
// 512 threads: waves 0-3 = 12 h0-rows (whh0+wih1, rh splits 6+6), waves 4-7 =
// 6 h1-rows (whh1, rh splits 3+3). out2 staged in LDS, written coalesced
// post-loop (removes 32 scattered dwords from every phase's fence drain).
// gi0 gate inputs prefetched at phase top -> latency hides under GEMV.
__global__ __launch_bounds__(512, 2) void k_gru(
        const float* __restrict__ gi0,
        const float* __restrict__ wih1, const float* __restrict__ whh0,
        const float* __restrict__ whh1,
        const float* __restrict__ bih1, const float* __restrict__ bhh0,
        const float* __restrict__ bhh1,
        float* __restrict__ h0a, float* __restrict__ h0b,
        float* __restrict__ h1a, float* __restrict__ h1b,
        float* __restrict__ out, int* bar){
    __shared__ float wsm[18 * HID];            // rows 0-5: whh0, 6-11: wih1, 12-17: whh1
    __shared__ float part[18 * NSLC * PPAD];   // [row][ks][b(+pad)]
    __shared__ float ghl[18 * 32];
    __shared__ float outst[SEQ * 64];          // [step][bb*2+l] staged out2

    int tid = threadIdx.x;
    int i0 = blockIdx.x * 2;

    #pragma unroll
    for (int r = 0; r < 6; r++){
        int j = (r >> 1) * HID + i0 + (r & 1);
        for (int k = tid; k < HID; k += 512){
            wsm[r * HID + k]        = whh0[(size_t)j * HID + k];
            wsm[(6 + r) * HID + k]  = wih1[(size_t)j * HID + k];
            wsm[(12 + r) * HID + k] = whh1[(size_t)j * HID + k];
        }
    }
    __syncthreads();

    int t8  = tid & 255;
    int bq  = t8 & 7;                 // batch quad: batches 4bq..4bq+3
    int ks  = (t8 >> 3) & (NSLC - 1); // k-slice
    int rh  = t8 >> 7;                // row half within group
    int l   = (tid >> 5) & 1, bb = tid & 31;   // gate-thread coords (tid<64)
    int i   = i0 + l;
    float hs0 = 0.f, hs1 = 0.f;       // registered h state for own unit (tid<64)

    // hoisted per-unit biases (tid<64 only uses them)
    float bh0r = bhh0[i], bh0z = bhh0[HID + i], bh0n = bhh0[2 * HID + i];
    float bi1r = bih1[i], bi1z = bih1[HID + i], bi1n = bih1[2 * HID + i];
    float bh1r = bhh1[i], bh1z = bhh1[HID + i], bh1n = bhh1[2 * HID + i];

    for (int p = 0; p <= SEQ; p++){
        const float* h0r = (p & 1) ? h0a : h0b;   // h0(p-1)  (also = out1(p-1))
        float*       h0w = (p & 1) ? h0b : h0a;   // h0(p)
        const float* h1r = (p & 1) ? h1b : h1a;   // h1(p-2)
        float*       h1w = (p & 1) ? h1a : h1b;   // h1(p-1)

        // prefetch this phase's gi gate inputs (independent of h) early
        float giR = 0.f, giZ = 0.f, giN = 0.f;
        if (tid < 64 && p < SEQ){
            const float* gi = gi0 + (size_t)(p * BATCH + bb) * G3;
            giR = gi[i]; giZ = gi[HID + i]; giN = gi[2 * HID + i];
        }

        if (tid < 256) gemv_part<6>(h0r, wsm + (rh * 6) * HID,
                                    part + (rh * 6) * NSLC * PPAD, bq, ks);
        else           gemv_part<3>(h1r, wsm + (12 + rh * 3) * HID,
                                    part + (12 + rh * 3) * NSLC * PPAD, bq, ks);
        __syncthreads();

        // stage-2 reduce over NSLC slices -> ghl[row][b]
        for (int o = tid; o < 18 * 32; o += 512){
            int row = o >> 5, b2 = o & 31;
            float sum = 0.f;
            #pragma unroll
            for (int q = 0; q < NSLC; q++) sum += part[(row * NSLC + q) * PPAD + b2];
            ghl[row * 32 + b2] = sum;
        }
        __syncthreads();

        if (tid < 64){
            if (p < SEQ){   // layer0 step p
                float ghr = ghl[(0 + l) * 32 + bb] + bh0r;
                float ghz = ghl[(2 + l) * 32 + bb] + bh0z;
                float ghn = ghl[(4 + l) * 32 + bb] + bh0n;
                float rr = sigmoidf(giR + ghr);
                float zz = sigmoidf(giZ + ghz);
                float nn = tanhf(giN + rr * ghn);
                hs0 = (1.f - zz) * nn + zz * hs0;
                h0w[i * 32 + bb] = hs0;
            }
            if (p >= 1){    // layer1 step p-1
                float gir = ghl[(6 + l) * 32 + bb]  + bi1r;
                float giz = ghl[(8 + l) * 32 + bb]  + bi1z;
                float gin = ghl[(10 + l) * 32 + bb] + bi1n;
                float ghr = ghl[(12 + l) * 32 + bb] + bh1r;
                float ghz = ghl[(14 + l) * 32 + bb] + bh1z;
                float ghn = ghl[(16 + l) * 32 + bb] + bh1n;
                float rr = sigmoidf(gir + ghr);
                float zz = sigmoidf(giz + ghz);
                float nn = tanhf(gin + rr * ghn);
                hs1 = (1.f - zz) * nn + zz * hs1;
                h1w[i * 32 + bb] = hs1;
                outst[(p - 1) * 64 + bb * 2 + l] = hs1;   // staged out2[p-1,b,i]
            }
        }
        if (p < SEQ) grid_barrier(bar, p + 1);
    }

    __syncthreads();
    // coalesced out2 write: 480 float2 stores (this block owns cols i0,i0+1)
    for (int o = tid; o < SEQ * 32; o += 512){
        int q = o >> 5, b2 = o & 31;
        float2 v = *(float2*)&outst[q * 64 + b2 * 2];
        *(float2*)&out[(size_t)(q * BATCH + b2) * HID + i0] = v;
    }
    // hn from registered state: h0(14), h1(14)
    if (tid < 64){
        out[SEQ * BATCH * HID + (size_t)bb * HID + i] = hs0;
        out[SEQ * BATCH * HID + BATCH * HID + (size_t)bb * HID + i] = hs1;
    }
}

extern "C" void kernel_launch(void* const* d_in, const int* in_sizes, int n_in,
                              void* d_out, int out_size, void* d_ws, size_t ws_size,
                              hipStream_t stream){
    (void)in_sizes; (void)n_in; (void)out_size; (void)ws_size;
    const float* x    = (const float*)d_in[0];
    const int*   ei   = (const int*)d_in[1];
    const float* W1   = (const float*)d_in[2];
    const float* b1   = (const float*)d_in[3];
    const float* W2   = (const float*)d_in[4];
    const float* b2   = (const float*)d_in[5];
    const float* wih0 = (const float*)d_in[6];
    const float* whh0 = (const float*)d_in[7];
    const float* bih0 = (const float*)d_in[8];
    const float* bhh0 = (const float*)d_in[9];
    const float* wih1 = (const float*)d_in[10];
    const float* whh1 = (const float*)d_in[11];
    const float* bih1 = (const float*)d_in[12];
    const float* bhh1 = (const float*)d_in[13];
    float* out = (float*)d_out;

    char* w = (char*)d_ws;
    auto alloc = [&](size_t bytes) -> char* {
        char* p = w; w += (bytes + 255) & ~(size_t)255; return p;
    };
    float* dinv   = (float*)alloc(NNODES * 4);
    int*   counts = (int*)  alloc(NNODES * 4);
    int*   offs   = (int*)  alloc((NNODES + 8) * 4);
    int*   fill   = (int*)  alloc(NNODES * 4);
    int*   csr    = (int*)  alloc(NEDGES * 4);
    int*   bar    = (int*)  alloc(BAR_INTS * 4);
    float* h0a    = (float*)alloc(HID * BATCH * 4);
    float* h0b    = (float*)alloc(HID * BATCH * 4);
    float* h1a    = (float*)alloc(HID * BATCH * 4);
    float* h1b    = (float*)alloc(HID * BATCH * 4);
    float* h1s    = (float*)alloc((size_t)SEQ * BATCH * NNODES * 2 * 4);
    float* h2s    = (float*)alloc((size_t)SEQ * BATCH * NNODES * 4);
    float* gbuf   = (float*)alloc((size_t)SEQ * BATCH * NNODES * 4);
    float* gi0    = (float*)alloc((size_t)SEQ * BATCH * G3 * 4);
    // split-K partials (9 * 480 * 1536 * 4 = 26.5 MB) alias the h1s+h2s
    // region (19.2 MB + 9.6 MB contiguous): h1s is dead after k_agg1, h2s
    // after k_agg2 -- both before k_gemm runs.
    float* part   = h1s;

    k_init <<<64, 256, 0, stream>>>(counts, fill, bar, h0a, h0b, h1a, h1b);
    k_count<<<(NEDGES + 255) / 256, 256, 0, stream>>>(ei, counts);
    k_dinv <<<(NNODES + 255) / 256, 256, 0, stream>>>(counts, dinv);
    k_scan <<<1, 1024, 0, stream>>>(counts, offs);
    k_fill <<<(NEDGES + 255) / 256, 256, 0, stream>>>(ei, offs, fill, csr);

    dim3 gconv((NNODES + 255) / 256, BATCH, SEQ);
    k_conv1<<<gconv, 256, 0, stream>>>(x, W1, dinv, h1s);
    k_agg1 <<<gconv, 256, 0, stream>>>(h1s, offs, csr, dinv, b1, W2, h2s);
    k_agg2 <<<gconv, 256, 0, stream>>>(h2s, offs, csr, dinv, b2, gbuf);

    k_gemm<<<dim3(G3 / 64, 8, KSPLIT), 256, 0, stream>>>(gbuf, wih0, part);
    k_gred<<<(MROWS * G3) / 256, 256, 0, stream>>>(part, bih0, gi0);

    k_gru<<<GRU_BLOCKS, 512, 0, stream>>>(gi0, wih1, whh0, whh1, bih1, bhh0, bhh1,
                                          h0a, h0b, h1a, h1b, out, bar);
}

// Round 4
// 1022.675 us; speedup vs baseline: 1.1174x; 1.1174x over previous
//
#include <hip/hip_runtime.h>

typedef unsigned int uint_t;

#define SEQ 15
#define BATCH 32
#define NNODES 5000
#define NEDGES 80000
#define INFEAT 16
#define HID 512
#define G3 1536   // 3*HID
#define GRU_BLOCKS 256
#define BAR_INTS (32 * (2 * GRU_BLOCKS))   // 256 slot lines + 256 flag lines

// split-K GEMM config
#define KSPLIT 9
#define KCHUNK 576          // 9*576 = 5184 >= 5000; last chunk = 392
#define MROWS 480           // SEQ*BATCH
#define LDSP 68             // padded LDS row stride (64 + 4): 2-way banks (free)

// GRU GEMV config
#define NSLC 16             // k-slices (each thread covers 32 k, strided)
#define PPAD 36             // part row pad (multiple of 4; 2-way banks on write)

__device__ __forceinline__ float sigmoidf(float x){ return 1.0f / (1.0f + __expf(-x)); }

// ---------------- init ----------------
__global__ void k_init(int* counts, int* fill, int* bar,
                       float* h0a, float* h0b, float* h1a, float* h1b){
    int t = blockIdx.x * 256 + threadIdx.x;   // 0..16383
    if (t < NNODES){ counts[t] = 0; fill[t] = 0; }
    if (t < BAR_INTS) bar[t] = 0;
    h0a[t] = 0.f; h0b[t] = 0.f; h1a[t] = 0.f; h1b[t] = 0.f;
}

// ---------------- degree count (by target col) ----------------
__global__ void k_count(const int* ei, int* counts){
    int e = blockIdx.x * 256 + threadIdx.x;
    if (e < NEDGES) atomicAdd(&counts[ei[NEDGES + e]], 1);
}

__global__ void k_dinv(const int* counts, float* dinv){
    int n = blockIdx.x * 256 + threadIdx.x;
    if (n < NNODES) dinv[n] = rsqrtf(1.0f + (float)counts[n]);  // +1 self loop
}

// ---------------- exclusive scan of counts -> offs (single block) ----------------
__global__ void k_scan(const int* counts, int* offs){
    __shared__ int sdata[1024];
    int tid = threadIdx.x;
    int base = tid * 5;
    int loc[5]; int tot = 0;
    #pragma unroll
    for (int q = 0; q < 5; q++){
        int idx = base + q;
        int v = (idx < NNODES) ? counts[idx] : 0;
        loc[q] = tot; tot += v;
    }
    sdata[tid] = tot; __syncthreads();
    for (int off = 1; off < 1024; off <<= 1){
        int t = (tid >= off) ? sdata[tid - off] : 0;
        __syncthreads();
        sdata[tid] += t;
        __syncthreads();
    }
    int excl = sdata[tid] - tot;
    #pragma unroll
    for (int q = 0; q < 5; q++){
        int idx = base + q;
        if (idx < NNODES) offs[idx] = excl + loc[q];
    }
    if (tid == 1023) offs[NNODES] = sdata[1023];
}

// ---------------- CSR fill: bucket sources by target ----------------
__global__ void k_fill(const int* ei, const int* offs, int* fill, int* csr){
    int e = blockIdx.x * 256 + threadIdx.x;
    if (e < NEDGES){
        int c = ei[NEDGES + e];
        int p = offs[c] + atomicAdd(&fill[c], 1);
        csr[p] = ei[e];
    }
}

// ---------------- conv1 linear: h1s[s,b,n,{0,1}] = dinv[n] * (x[s,b,n,:] @ W1[s]) ----------------
__global__ void k_conv1(const float* x, const float* W1, const float* dinv, float* h1s){
    int n = blockIdx.x * 256 + threadIdx.x;
    int b = blockIdx.y, s = blockIdx.z;
    if (n >= NNODES) return;
    float w[32];
    #pragma unroll
    for (int q = 0; q < 32; q++) w[q] = W1[s * 32 + q];   // s uniform -> scalar loads
    size_t idx = ((size_t)(s * BATCH + b) * NNODES + n);
    const float4* xp = (const float4*)(x + idx * INFEAT);
    float4 u0 = xp[0], u1 = xp[1], u2 = xp[2], u3 = xp[3];
    float xs[16] = { u0.x,u0.y,u0.z,u0.w, u1.x,u1.y,u1.z,u1.w,
                     u2.x,u2.y,u2.z,u2.w, u3.x,u3.y,u3.z,u3.w };
    float a0 = 0.f, a1 = 0.f;
    #pragma unroll
    for (int f = 0; f < 16; f++){ a0 += xs[f] * w[2 * f]; a1 += xs[f] * w[2 * f + 1]; }
    float d = dinv[n];
    ((float2*)h1s)[idx] = make_float2(d * a0, d * a1);
}

// ------- aggregate1 + bias + relu + conv2 linear + pre-scale: h2s = dinv * (relu(dinv*agg + b1) @ W2) -------
__global__ void k_agg1(const float* h1s, const int* offs, const int* csr, const float* dinv,
                       const float* b1, const float* W2, float* h2s){
    int n = blockIdx.x * 256 + threadIdx.x;
    int b = blockIdx.y, s = blockIdx.z;
    if (n >= NNODES) return;
    size_t base = (size_t)(s * BATCH + b) * NNODES;
    const float2* hp = (const float2*)h1s + base;
    float2 self = hp[n];
    float a0 = self.x, a1 = self.y;
    int p1 = offs[n + 1];
    for (int p = offs[n]; p < p1; p++){
        float2 v = hp[csr[p]];
        a0 += v.x; a1 += v.y;
    }
    float d = dinv[n];
    float r0 = fmaxf(d * a0 + b1[s * 2 + 0], 0.f);
    float r1 = fmaxf(d * a1 + b1[s * 2 + 1], 0.f);
    float t2 = r0 * W2[s * 2 + 0] + r1 * W2[s * 2 + 1];
    h2s[base + n] = d * t2;
}

// ------- aggregate2 + bias + tanh -> g[s*32+b][n] -------
__global__ void k_agg2(const float* h2s, const int* offs, const int* csr, const float* dinv,
                       const float* b2, float* g){
    int n = blockIdx.x * 256 + threadIdx.x;
    int b = blockIdx.y, s = blockIdx.z;
    if (n >= NNODES) return;
    size_t base = (size_t)(s * BATCH + b) * NNODES;
    const float* hp = h2s + base;
    float a = hp[n];
    int p1 = offs[n + 1];
    for (int p = offs[n]; p < p1; p++) a += hp[csr[p]];
    g[base + n] = tanhf(dinv[n] * a + b2[s]);
}

// ------- split-K GEMM: part[z][480][1536] += A[480][kz] @ W[1536][kz]^T -------
__global__ __launch_bounds__(256) void k_gemm(const float* A, const float* W,
                                              float* part){
    __shared__ float As[16 * LDSP];
    __shared__ float Bs[16 * LDSP];
    int tid = threadIdx.x;
    int j0 = blockIdx.x * 64;   // N tile (1536/64 = 24)
    int m0 = blockIdx.y * 64;   // M tile (ceil(480/64) = 8)
    int kz = blockIdx.z;        // K split
    int kbeg = kz * KCHUNK;
    int kend = kbeg + KCHUNK; if (kend > 5000) kend = 5000;
    int tm = tid >> 4, tn = tid & 15;
    int lr = tid >> 2;           // 0..63
    int lk = (tid & 3) * 4;      // 0,4,8,12
    float acc[4][4];
    #pragma unroll
    for (int i = 0; i < 4; i++)
        #pragma unroll
        for (int j = 0; j < 4; j++) acc[i][j] = 0.f;

    for (int k0 = kbeg; k0 < kend; k0 += 16){
        int m = m0 + lr;
        float4 av = make_float4(0.f, 0.f, 0.f, 0.f);
        if (m < MROWS && (k0 + lk) < 5000)
            av = *(const float4*)&A[(size_t)m * 5000 + k0 + lk];
        As[(lk + 0) * LDSP + lr] = av.x; As[(lk + 1) * LDSP + lr] = av.y;
        As[(lk + 2) * LDSP + lr] = av.z; As[(lk + 3) * LDSP + lr] = av.w;
        int j = j0 + lr;
        float4 bv = make_float4(0.f, 0.f, 0.f, 0.f);
        if ((k0 + lk) < 5000)
            bv = *(const float4*)&W[(size_t)j * 5000 + k0 + lk];
        Bs[(lk + 0) * LDSP + lr] = bv.x; Bs[(lk + 1) * LDSP + lr] = bv.y;
        Bs[(lk + 2) * LDSP + lr] = bv.z; Bs[(lk + 3) * LDSP + lr] = bv.w;
        __syncthreads();
        #pragma unroll
        for (int k = 0; k < 16; k++){
            float4 a = *(float4*)&As[k * LDSP + tm * 4];
            float4 bb = *(float4*)&Bs[k * LDSP + tn * 4];
            acc[0][0] += a.x * bb.x; acc[0][1] += a.x * bb.y; acc[0][2] += a.x * bb.z; acc[0][3] += a.x * bb.w;
            acc[1][0] += a.y * bb.x; acc[1][1] += a.y * bb.y; acc[1][2] += a.y * bb.z; acc[1][3] += a.y * bb.w;
            acc[2][0] += a.z * bb.x; acc[2][1] += a.z * bb.y; acc[2][2] += a.z * bb.z; acc[2][3] += a.z * bb.w;
            acc[3][0] += a.w * bb.x; acc[3][1] += a.w * bb.y; acc[3][2] += a.w * bb.z; acc[3][3] += a.w * bb.w;
        }
        __syncthreads();
    }
    size_t zbase = (size_t)kz * MROWS * G3;
    #pragma unroll
    for (int i = 0; i < 4; i++){
        int m = m0 + tm * 4 + i;
        if (m < MROWS){
            #pragma unroll
            for (int j = 0; j < 4; j++){
                int col = j0 + tn * 4 + j;
                part[zbase + (size_t)m * G3 + col] = acc[i][j];
            }
        }
    }
}

// ------- reduce split-K partials + bias -> gi0 -------
__global__ __launch_bounds__(256) void k_gred(const float* part, const float* bias, float* C){
    int idx = blockIdx.x * 256 + threadIdx.x;   // 0 .. 480*1536-1
    float s = bias[idx % G3];
    float sum = 0.f;
    #pragma unroll
    for (int z = 0; z < KSPLIT; z++)
        sum += part[(size_t)z * MROWS * G3 + idx];
    C[idx] = sum + s;
}

// ------- contention-free grid barrier -----------------------------------------
__device__ __forceinline__ void grid_barrier(int* bar, int phase){
    __syncthreads();
    if (threadIdx.x == 0){
        __threadfence();   // release: drain this block's global writes
        __hip_atomic_store(&bar[32 * blockIdx.x], phase,
                           __ATOMIC_RELAXED, __HIP_MEMORY_SCOPE_AGENT);
    }
    if (blockIdx.x == 0 && threadIdx.x < 64){
        int lane = threadIdx.x;
        for (;;){
            int mn = 0x7fffffff;
            #pragma unroll
            for (int q = 0; q < 4; q++){
                int v = __hip_atomic_load(&bar[32 * (lane + 64 * q)],
                                          __ATOMIC_RELAXED, __HIP_MEMORY_SCOPE_AGENT);
                mn = min(mn, v);
            }
            if (__all(mn >= phase)) break;
            __builtin_amdgcn_s_sleep(4);
        }
        __threadfence();   // acquire observed slots; order before flag stores
        #pragma unroll
        for (int q = 0; q < 4; q++)
            __hip_atomic_store(&bar[32 * (GRU_BLOCKS + lane + 64 * q)], phase,
                               __ATOMIC_RELAXED, __HIP_MEMORY_SCOPE_AGENT);
    }
    if (threadIdx.x == 0){
        while (__hip_atomic_load(&bar[32 * (GRU_BLOCKS + blockIdx.x)],
                                 __ATOMIC_RELAXED, __HIP_MEMORY_SCOPE_AGENT) < phase)
            __builtin_amdgcn_s_sleep(4);
        __threadfence();   // acquire: invalidate stale cached h-state
    }
    __syncthreads();
}

// ------- per-group partial GEMV: NR rows x 32 k (strided) x 4 batches ---------
// R8: #pragma unroll 2 on the j loop. R6/R7 let the compiler fully unroll and
// hoist all 8 iterations' global h loads (8x16 = 128 VGPRs of hv) against a
// 128-VGPR budget -> scratch spill; the per-phase agent-scope release fence
// then wrote the dirty scratch back to HBM EVERY phase (WRITE_SIZE 225MB,
// 748 GB/s of pure spill traffic). unroll 2 caps live hv at 32 regs; total
// live ~80 < 128 -> no spill, nothing for the fence to drain.
template<int NR>
__device__ __forceinline__ void gemv_part(const float* __restrict__ h,
                                          const float* __restrict__ wsm0,
                                          float* __restrict__ part0, int bq, int ks){
    float acc[NR][4];
    #pragma unroll
    for (int r = 0; r < NR; r++){ acc[r][0] = acc[r][1] = acc[r][2] = acc[r][3] = 0.f; }
    #pragma unroll 2
    for (int j = 0; j < 8; j++){
        int k = ks * 4 + j * 64;
        float4 hv0 = *(const float4*)&h[(k + 0) * 32 + 4 * bq];
        float4 hv1 = *(const float4*)&h[(k + 1) * 32 + 4 * bq];
        float4 hv2 = *(const float4*)&h[(k + 2) * 32 + 4 * bq];
        float4 hv3 = *(const float4*)&h[(k + 3) * 32 + 4 * bq];
        #pragma unroll
        for (int r = 0; r < NR; r++){
            float4 w = *(const float4*)&wsm0[r * HID + k];
            acc[r][0] += w.x * hv0.x + w.y * hv1.x + w.z * hv2.x + w.w * hv3.x;
            acc[r][1] += w.x * hv0.y + w.y * hv1.y + w.z * hv2.y + w.w * hv3.y;
            acc[r][2] += w.x * hv0.z + w.y * hv1.z + w.z * hv2.z + w.w * hv3.z;
            acc[r][3] += w.x * hv0.w + w.y * hv1.w + w.z * hv2.w + w.w * hv3.w;
        }
    }
    #pragma unroll
    for (int r = 0; r < NR; r++)
        *(float4*)&part0[(r * NSLC + ks) * PPAD + 4 * bq] =
            make_float4(acc[r][0], acc[r][1], acc[r][2], acc[r][3]);
}

// ------- persistent 2-layer GRU, layer-pipelined: ONE barrier per step --------
// 512 threads: waves 0-3 = 12 h0-rows (whh0+wih1, rh splits 6+6), waves 4-7 =
// 6 h1-rows (whh1, rh splits 3+3). out2 staged in LDS, written coalesced
// post-loop. gi0 gate inputs prefetched at phase top. Biases NOT hoisted
// (R7 regression: 9 extra live regs across the gemv on the tid<64 path).
__global__ __launch_bounds__(512, 2) void k_gru(
        const float* __restrict__ gi0,
        const float* __restrict__ wih1, const float* __restrict__ whh0,
        const float* __restrict__ whh1,
        const float* __restrict__ bih1, const float* __restrict__ bhh0,
        const float* __restrict__ bhh1,
        float* __restrict__ h0a, float* __restrict__ h0b,
        float* __restrict__ h1a, float* __restrict__ h1b,
        float* __restrict__ out, int* bar){
    __shared__ float wsm[18 * HID];            // rows 0-5: whh0, 6-11: wih1, 12-17: whh1
    __shared__ float part[18 * NSLC * PPAD];   // [row][ks][b(+pad)]
    __shared__ float ghl[18 * 32];
    __shared__ float outst[SEQ * 64];          // [step][bb*2+l] staged out2

    int tid = threadIdx.x;
    int i0 = blockIdx.x * 2;

    #pragma unroll
    for (int r = 0; r < 6; r++){
        int j = (r >> 1) * HID + i0 + (r & 1);
        for (int k = tid; k < HID; k += 512){
            wsm[r * HID + k]        = whh0[(size_t)j * HID + k];
            wsm[(6 + r) * HID + k]  = wih1[(size_t)j * HID + k];
            wsm[(12 + r) * HID + k] = whh1[(size_t)j * HID + k];
        }
    }
    __syncthreads();

    int t8  = tid & 255;
    int bq  = t8 & 7;                 // batch quad: batches 4bq..4bq+3
    int ks  = (t8 >> 3) & (NSLC - 1); // k-slice
    int rh  = t8 >> 7;                // row half within group
    int l   = (tid >> 5) & 1, bb = tid & 31;   // gate-thread coords (tid<64)
    int i   = i0 + l;
    float hs0 = 0.f, hs1 = 0.f;       // registered h state for own unit (tid<64)

    for (int p = 0; p <= SEQ; p++){
        const float* h0r = (p & 1) ? h0a : h0b;   // h0(p-1)  (also = out1(p-1))
        float*       h0w = (p & 1) ? h0b : h0a;   // h0(p)
        const float* h1r = (p & 1) ? h1b : h1a;   // h1(p-2)
        float*       h1w = (p & 1) ? h1a : h1b;   // h1(p-1)

        // prefetch this phase's gi gate inputs (independent of h) early
        float giR = 0.f, giZ = 0.f, giN = 0.f;
        if (tid < 64 && p < SEQ){
            const float* gi = gi0 + (size_t)(p * BATCH + bb) * G3;
            giR = gi[i]; giZ = gi[HID + i]; giN = gi[2 * HID + i];
        }

        if (tid < 256) gemv_part<6>(h0r, wsm + (rh * 6) * HID,
                                    part + (rh * 6) * NSLC * PPAD, bq, ks);
        else           gemv_part<3>(h1r, wsm + (12 + rh * 3) * HID,
                                    part + (12 + rh * 3) * NSLC * PPAD, bq, ks);
        __syncthreads();

        // stage-2 reduce over NSLC slices -> ghl[row][b]
        for (int o = tid; o < 18 * 32; o += 512){
            int row = o >> 5, b2 = o & 31;
            float sum = 0.f;
            #pragma unroll
            for (int q = 0; q < NSLC; q++) sum += part[(row * NSLC + q) * PPAD + b2];
            ghl[row * 32 + b2] = sum;
        }
        __syncthreads();

        if (tid < 64){
            if (p < SEQ){   // layer0 step p
                float ghr = ghl[(0 + l) * 32 + bb] + bhh0[i];
                float ghz = ghl[(2 + l) * 32 + bb] + bhh0[HID + i];
                float ghn = ghl[(4 + l) * 32 + bb] + bhh0[2 * HID + i];
                float rr = sigmoidf(giR + ghr);
                float zz = sigmoidf(giZ + ghz);
                float nn = tanhf(giN + rr * ghn);
                hs0 = (1.f - zz) * nn + zz * hs0;
                h0w[i * 32 + bb] = hs0;
            }
            if (p >= 1){    // layer1 step p-1
                float gir = ghl[(6 + l) * 32 + bb]  + bih1[i];
                float giz = ghl[(8 + l) * 32 + bb]  + bih1[HID + i];
                float gin = ghl[(10 + l) * 32 + bb] + bih1[2 * HID + i];
                float ghr = ghl[(12 + l) * 32 + bb] + bhh1[i];
                float ghz = ghl[(14 + l) * 32 + bb] + bhh1[HID + i];
                float ghn = ghl[(16 + l) * 32 + bb] + bhh1[2 * HID + i];
                float rr = sigmoidf(gir + ghr);
                float zz = sigmoidf(giz + ghz);
                float nn = tanhf(gin + rr * ghn);
                hs1 = (1.f - zz) * nn + zz * hs1;
                h1w[i * 32 + bb] = hs1;
                outst[(p - 1) * 64 + bb * 2 + l] = hs1;   // staged out2[p-1,b,i]
            }
        }
        if (p < SEQ) grid_barrier(bar, p + 1);
    }

    __syncthreads();
    // coalesced out2 write: 480 float2 stores (this block owns cols i0,i0+1)
    for (int o = tid; o < SEQ * 32; o += 512){
        int q = o >> 5, b2 = o & 31;
        float2 v = *(float2*)&outst[q * 64 + b2 * 2];
        *(float2*)&out[(size_t)(q * BATCH + b2) * HID + i0] = v;
    }
    // hn from registered state: h0(14), h1(14)
    if (tid < 64){
        out[SEQ * BATCH * HID + (size_t)bb * HID + i] = hs0;
        out[SEQ * BATCH * HID + BATCH * HID + (size_t)bb * HID + i] = hs1;
    }
}

extern "C" void kernel_launch(void* const* d_in, const int* in_sizes, int n_in,
                              void* d_out, int out_size, void* d_ws, size_t ws_size,
                              hipStream_t stream){
    (void)in_sizes; (void)n_in; (void)out_size; (void)ws_size;
    const float* x    = (const float*)d_in[0];
    const int*   ei   = (const int*)d_in[1];
    const float* W1   = (const float*)d_in[2];
    const float* b1   = (const float*)d_in[3];
    const float* W2   = (const float*)d_in[4];
    const float* b2   = (const float*)d_in[5];
    const float* wih0 = (const float*)d_in[6];
    const float* whh0 = (const float*)d_in[7];
    const float* bih0 = (const float*)d_in[8];
    const float* bhh0 = (const float*)d_in[9];
    const float* wih1 = (const float*)d_in[10];
    const float* whh1 = (const float*)d_in[11];
    const float* bih1 = (const float*)d_in[12];
    const float* bhh1 = (const float*)d_in[13];
    float* out = (float*)d_out;

    char* w = (char*)d_ws;
    auto alloc = [&](size_t bytes) -> char* {
        char* p = w; w += (bytes + 255) & ~(size_t)255; return p;
    };
    float* dinv   = (float*)alloc(NNODES * 4);
    int*   counts = (int*)  alloc(NNODES * 4);
    int*   offs   = (int*)  alloc((NNODES + 8) * 4);
    int*   fill   = (int*)  alloc(NNODES * 4);
    int*   csr    = (int*)  alloc(NEDGES * 4);
    int*   bar    = (int*)  alloc(BAR_INTS * 4);
    float* h0a    = (float*)alloc(HID * BATCH * 4);
    float* h0b    = (float*)alloc(HID * BATCH * 4);
    float* h1a    = (float*)alloc(HID * BATCH * 4);
    float* h1b    = (float*)alloc(HID * BATCH * 4);
    float* h1s    = (float*)alloc((size_t)SEQ * BATCH * NNODES * 2 * 4);
    float* h2s    = (float*)alloc((size_t)SEQ * BATCH * NNODES * 4);
    float* gbuf   = (float*)alloc((size_t)SEQ * BATCH * NNODES * 4);
    float* gi0    = (float*)alloc((size_t)SEQ * BATCH * G3 * 4);
    // split-K partials (9 * 480 * 1536 * 4 = 26.5 MB) alias the h1s+h2s
    // region (19.2 MB + 9.6 MB contiguous): h1s is dead after k_agg1, h2s
    // after k_agg2 -- both before k_gemm runs.
    float* part   = h1s;

    k_init <<<64, 256, 0, stream>>>(counts, fill, bar, h0a, h0b, h1a, h1b);
    k_count<<<(NEDGES + 255) / 256, 256, 0, stream>>>(ei, counts);
    k_dinv <<<(NNODES + 255) / 256, 256, 0, stream>>>(counts, dinv);
    k_scan <<<1, 1024, 0, stream>>>(counts, offs);
    k_fill <<<(NEDGES + 255) / 256, 256, 0, stream>>>(ei, offs, fill, csr);

    dim3 gconv((NNODES + 255) / 256, BATCH, SEQ);
    k_conv1<<<gconv, 256, 0, stream>>>(x, W1, dinv, h1s);
    k_agg1 <<<gconv, 256, 0, stream>>>(h1s, offs, csr, dinv, b1, W2, h2s);
    k_agg2 <<<gconv, 256, 0, stream>>>(h2s, offs, csr, dinv, b2, gbuf);

    k_gemm<<<dim3(G3 / 64, 8, KSPLIT), 256, 0, stream>>>(gbuf, wih0, part);
    k_gred<<<(MROWS * G3) / 256, 256, 0, stream>>>(part, bih0, gi0);

    k_gru<<<GRU_BLOCKS, 512, 0, stream>>>(gi0, wih1, whh0, whh1, bih1, bhh0, bhh1,
                                          h0a, h0b, h1a, h1b, out, bar);
}

// Round 5
// 887.571 us; speedup vs baseline: 1.2875x; 1.1522x over previous
//
#include <hip/hip_runtime.h>

typedef unsigned int uint_t;

#define SEQ 15
#define BATCH 32
#define NNODES 5000
#define NEDGES 80000
#define INFEAT 16
#define HID 512
#define G3 1536   // 3*HID
#define GRU_BLOCKS 256
#define BAR_INTS (32 * (2 * GRU_BLOCKS))   // 256 slot lines + 256 flag lines

// split-K GEMM config
#define KSPLIT 9
#define KCHUNK 576          // 9*576 = 5184 >= 5000; last chunk = 392
#define MROWS 480           // SEQ*BATCH
#define LDSP 68             // padded LDS row stride (64 + 4): 2-way banks (free)

// GRU GEMV config
#define NSLC 16             // k-slices (each thread covers 32 k, strided)
#define PPAD 36             // part row pad (multiple of 4; 2-way banks on write)

#define NT64 ((NNODES + 63) / 64)   // 79 node tiles of 64

__device__ __forceinline__ float sigmoidf(float x){ return 1.0f / (1.0f + __expf(-x)); }

// ---------------- init ----------------
__global__ void k_init(int* counts, int* fill, int* bar,
                       float* h0a, float* h0b, float* h1a, float* h1b){
    int t = blockIdx.x * 256 + threadIdx.x;   // 0..16383
    if (t < NNODES){ counts[t] = 0; fill[t] = 0; }
    if (t < BAR_INTS) bar[t] = 0;
    h0a[t] = 0.f; h0b[t] = 0.f; h1a[t] = 0.f; h1b[t] = 0.f;
}

// ---------------- degree count (by target col) ----------------
__global__ void k_count(const int* ei, int* counts){
    int e = blockIdx.x * 256 + threadIdx.x;
    if (e < NEDGES) atomicAdd(&counts[ei[NEDGES + e]], 1);
}

__global__ void k_dinv(const int* counts, float* dinv){
    int n = blockIdx.x * 256 + threadIdx.x;
    if (n < NNODES) dinv[n] = rsqrtf(1.0f + (float)counts[n]);  // +1 self loop
}

// ---------------- exclusive scan of counts -> offs (single block) ----------------
__global__ void k_scan(const int* counts, int* offs){
    __shared__ int sdata[1024];
    int tid = threadIdx.x;
    int base = tid * 5;
    int loc[5]; int tot = 0;
    #pragma unroll
    for (int q = 0; q < 5; q++){
        int idx = base + q;
        int v = (idx < NNODES) ? counts[idx] : 0;
        loc[q] = tot; tot += v;
    }
    sdata[tid] = tot; __syncthreads();
    for (int off = 1; off < 1024; off <<= 1){
        int t = (tid >= off) ? sdata[tid - off] : 0;
        __syncthreads();
        sdata[tid] += t;
        __syncthreads();
    }
    int excl = sdata[tid] - tot;
    #pragma unroll
    for (int q = 0; q < 5; q++){
        int idx = base + q;
        if (idx < NNODES) offs[idx] = excl + loc[q];
    }
    if (tid == 1023) offs[NNODES] = sdata[1023];
}

// ---------------- CSR fill: bucket sources by target ----------------
__global__ void k_fill(const int* ei, const int* offs, int* fill, int* csr){
    int e = blockIdx.x * 256 + threadIdx.x;
    if (e < NEDGES){
        int c = ei[NEDGES + e];
        int p = offs[c] + atomicAdd(&fill[c], 1);
        csr[p] = ei[e];
    }
}

// ------- conv1 linear -> TRANSPOSED h1t[s][n][b][{c0,c1}] -----------------
// R9: batch-major layout so the aggregation gathers coalesce. Reads of x stay
// coalesced (lane = node); the float2 writes scatter at 256B stride -- cheap
// next to the 153MB read stream.
__global__ __launch_bounds__(256) void k_conv1(const float* __restrict__ x,
        const float* __restrict__ W1, const float* __restrict__ dinv,
        float* __restrict__ h1t){
    int s = blockIdx.y;
    int nn = threadIdx.x & 63;
    int n  = blockIdx.x * 64 + nn;
    int bq = threadIdx.x >> 6;    // 0..3 -> batches bq*8 .. bq*8+7
    if (n >= NNODES) return;
    float w[32];
    #pragma unroll
    for (int q = 0; q < 32; q++) w[q] = W1[s * 32 + q];   // s uniform -> scalar loads
    float d = dinv[n];
    size_t sbase = (size_t)s * NNODES;
    for (int j = 0; j < 8; j++){
        int b = bq * 8 + j;
        const float4* xp = (const float4*)(x + ((size_t)(s * BATCH + b) * NNODES + n) * INFEAT);
        float4 u0 = xp[0], u1 = xp[1], u2 = xp[2], u3 = xp[3];
        float xs[16] = { u0.x,u0.y,u0.z,u0.w, u1.x,u1.y,u1.z,u1.w,
                         u2.x,u2.y,u2.z,u2.w, u3.x,u3.y,u3.z,u3.w };
        float a0 = 0.f, a1 = 0.f;
        #pragma unroll
        for (int f = 0; f < 16; f++){ a0 += xs[f] * w[2 * f]; a1 += xs[f] * w[2 * f + 1]; }
        ((float2*)h1t)[(sbase + n) * 32 + b] = make_float2(d * a0, d * a1);
    }
}

// ------- aggregate1 + bias + relu + conv2 + pre-scale (wave per node) ---------
// R9: lane = (b,c) plane (l = b*2+c). Per edge: ONE contiguous 256B wave-load
// (was 32 redundant random scalar gathers + 32 redundant index loads across
// batches). offs/csr/dinv loads are wave-uniform broadcasts. No degree
// divergence (trip count uniform per wave). Same FP order as before.
__global__ __launch_bounds__(256) void k_agg1(const float* __restrict__ h1t,
        const int* __restrict__ offs, const int* __restrict__ csr,
        const float* __restrict__ dinv, const float* __restrict__ b1,
        const float* __restrict__ W2, float* __restrict__ h2t){
    int s = blockIdx.y;
    int n0 = blockIdx.x * 64;
    int wv = threadIdx.x >> 6, l = threadIdx.x & 63;
    float w20 = W2[s * 2 + 0], w21 = W2[s * 2 + 1];
    float bb1 = b1[s * 2 + (l & 1)];
    size_t sbase = (size_t)s * NNODES;
    for (int r = 0; r < 16; r++){
        int n = n0 + wv + 4 * r;          // wave-uniform
        if (n >= NNODES) continue;
        const float* hp = h1t + (sbase + n) * 64;
        float acc = hp[l];                 // self (pre-scaled by dinv[src]=dinv[n])
        int e0 = offs[n], e1 = offs[n + 1];
        for (int p = e0; p < e1; p++){
            int src = csr[p];              // broadcast
            acc += h1t[(sbase + src) * 64 + l];   // coalesced 256B
        }
        float d = dinv[n];
        float val = fmaxf(d * acc + bb1, 0.f);
        float oth = __shfl_xor(val, 1);    // partner channel, same b
        if ((l & 1) == 0)
            h2t[(sbase + n) * 32 + (l >> 1)] = d * (val * w20 + oth * w21);
    }
}

// ------- aggregate2 + bias + tanh (wave per node, 2 edges/iter) ---------------
// lanes: half = l>>5 walks alternate edges, bl = batch. Final g written back in
// the ORIGINAL [s*32+b][n] layout via an LDS transpose tile -> k_gemm unchanged.
__global__ __launch_bounds__(256) void k_agg2(const float* __restrict__ h2t,
        const int* __restrict__ offs, const int* __restrict__ csr,
        const float* __restrict__ dinv, const float* __restrict__ b2,
        float* __restrict__ g){
    __shared__ float gst[64 * 33];
    int s = blockIdx.y;
    int n0 = blockIdx.x * 64;
    int wv = threadIdx.x >> 6, l = threadIdx.x & 63;
    int half = l >> 5, bl = l & 31;
    float bs = b2[s];
    size_t sbase = (size_t)s * NNODES;
    for (int r = 0; r < 16; r++){
        int n = n0 + wv + 4 * r;          // wave-uniform
        if (n < NNODES){
            float acc = half ? 0.f : h2t[(sbase + n) * 32 + bl];   // self once
            int e0 = offs[n], e1 = offs[n + 1];
            for (int p = e0 + half; p < e1; p += 2){
                int src = csr[p];
                acc += h2t[(sbase + src) * 32 + bl];   // coalesced 128B x2 halves
            }
            acc += __shfl_xor(acc, 32);    // combine the two edge-halves
            if (half == 0)
                gst[(wv + 4 * r) * 33 + bl] = tanhf(dinv[n] * acc + bs);
        }
    }
    __syncthreads();
    // coalesced write-out: g[(s*32+b)*N + n0+nn], 256B rows
    #pragma unroll
    for (int q = 0; q < 8; q++){
        int flat = q * 256 + threadIdx.x;   // 0..2047
        int b = flat >> 6, nn = flat & 63;
        int n = n0 + nn;
        if (n < NNODES)
            g[((size_t)s * BATCH + b) * NNODES + n] = gst[nn * 33 + b];
    }
}

// ------- split-K GEMM: part[z][480][1536] += A[480][kz] @ W[1536][kz]^T -------
__global__ __launch_bounds__(256) void k_gemm(const float* A, const float* W,
                                              float* part){
    __shared__ float As[16 * LDSP];
    __shared__ float Bs[16 * LDSP];
    int tid = threadIdx.x;
    int j0 = blockIdx.x * 64;   // N tile (1536/64 = 24)
    int m0 = blockIdx.y * 64;   // M tile (ceil(480/64) = 8)
    int kz = blockIdx.z;        // K split
    int kbeg = kz * KCHUNK;
    int kend = kbeg + KCHUNK; if (kend > 5000) kend = 5000;
    int tm = tid >> 4, tn = tid & 15;
    int lr = tid >> 2;           // 0..63
    int lk = (tid & 3) * 4;      // 0,4,8,12
    float acc[4][4];
    #pragma unroll
    for (int i = 0; i < 4; i++)
        #pragma unroll
        for (int j = 0; j < 4; j++) acc[i][j] = 0.f;

    for (int k0 = kbeg; k0 < kend; k0 += 16){
        int m = m0 + lr;
        float4 av = make_float4(0.f, 0.f, 0.f, 0.f);
        if (m < MROWS && (k0 + lk) < 5000)
            av = *(const float4*)&A[(size_t)m * 5000 + k0 + lk];
        As[(lk + 0) * LDSP + lr] = av.x; As[(lk + 1) * LDSP + lr] = av.y;
        As[(lk + 2) * LDSP + lr] = av.z; As[(lk + 3) * LDSP + lr] = av.w;
        int j = j0 + lr;
        float4 bv = make_float4(0.f, 0.f, 0.f, 0.f);
        if ((k0 + lk) < 5000)
            bv = *(const float4*)&W[(size_t)j * 5000 + k0 + lk];
        Bs[(lk + 0) * LDSP + lr] = bv.x; Bs[(lk + 1) * LDSP + lr] = bv.y;
        Bs[(lk + 2) * LDSP + lr] = bv.z; Bs[(lk + 3) * LDSP + lr] = bv.w;
        __syncthreads();
        #pragma unroll
        for (int k = 0; k < 16; k++){
            float4 a = *(float4*)&As[k * LDSP + tm * 4];
            float4 bb = *(float4*)&Bs[k * LDSP + tn * 4];
            acc[0][0] += a.x * bb.x; acc[0][1] += a.x * bb.y; acc[0][2] += a.x * bb.z; acc[0][3] += a.x * bb.w;
            acc[1][0] += a.y * bb.x; acc[1][1] += a.y * bb.y; acc[1][2] += a.y * bb.z; acc[1][3] += a.y * bb.w;
            acc[2][0] += a.z * bb.x; acc[2][1] += a.z * bb.y; acc[2][2] += a.z * bb.z; acc[2][3] += a.z * bb.w;
            acc[3][0] += a.w * bb.x; acc[3][1] += a.w * bb.y; acc[3][2] += a.w * bb.z; acc[3][3] += a.w * bb.w;
        }
        __syncthreads();
    }
    size_t zbase = (size_t)kz * MROWS * G3;
    #pragma unroll
    for (int i = 0; i < 4; i++){
        int m = m0 + tm * 4 + i;
        if (m < MROWS){
            #pragma unroll
            for (int j = 0; j < 4; j++){
                int col = j0 + tn * 4 + j;
                part[zbase + (size_t)m * G3 + col] = acc[i][j];
            }
        }
    }
}

// ------- reduce split-K partials + bias -> gi0 -------
__global__ __launch_bounds__(256) void k_gred(const float* part, const float* bias, float* C){
    int idx = blockIdx.x * 256 + threadIdx.x;   // 0 .. 480*1536-1
    float s = bias[idx % G3];
    float sum = 0.f;
    #pragma unroll
    for (int z = 0; z < KSPLIT; z++)
        sum += part[(size_t)z * MROWS * G3 + idx];
    C[idx] = sum + s;
}

// ------- contention-free grid barrier -----------------------------------------
__device__ __forceinline__ void grid_barrier(int* bar, int phase){
    __syncthreads();
    if (threadIdx.x == 0){
        __threadfence();   // release: drain this block's global writes
        __hip_atomic_store(&bar[32 * blockIdx.x], phase,
                           __ATOMIC_RELAXED, __HIP_MEMORY_SCOPE_AGENT);
    }
    if (blockIdx.x == 0 && threadIdx.x < 64){
        int lane = threadIdx.x;
        for (;;){
            int mn = 0x7fffffff;
            #pragma unroll
            for (int q = 0; q < 4; q++){
                int v = __hip_atomic_load(&bar[32 * (lane + 64 * q)],
                                          __ATOMIC_RELAXED, __HIP_MEMORY_SCOPE_AGENT);
                mn = min(mn, v);
            }
            if (__all(mn >= phase)) break;
            __builtin_amdgcn_s_sleep(4);
        }
        __threadfence();   // acquire observed slots; order before flag stores
        #pragma unroll
        for (int q = 0; q < 4; q++)
            __hip_atomic_store(&bar[32 * (GRU_BLOCKS + lane + 64 * q)], phase,
                               __ATOMIC_RELAXED, __HIP_MEMORY_SCOPE_AGENT);
    }
    if (threadIdx.x == 0){
        while (__hip_atomic_load(&bar[32 * (GRU_BLOCKS + blockIdx.x)],
                                 __ATOMIC_RELAXED, __HIP_MEMORY_SCOPE_AGENT) < phase)
            __builtin_amdgcn_s_sleep(4);
        __threadfence();   // acquire: invalidate stale cached h-state
    }
    __syncthreads();
}

// ------- per-group partial GEMV: NR rows x 32 k (strided) x 4 batches ---------
// R8: #pragma unroll 2 caps live hv regs; full unroll spilled and the per-phase
// release fence wrote dirty scratch to HBM every phase (225MB/dispatch).
template<int NR>
__device__ __forceinline__ void gemv_part(const float* __restrict__ h,
                                          const float* __restrict__ wsm0,
                                          float* __restrict__ part0, int bq, int ks){
    float acc[NR][4];
    #pragma unroll
    for (int r = 0; r < NR; r++){ acc[r][0] = acc[r][1] = acc[r][2] = acc[r][3] = 0.f; }
    #pragma unroll 2
    for (int j = 0; j < 8; j++){
        int k = ks * 4 + j * 64;
        float4 hv0 = *(const float4*)&h[(k + 0) * 32 + 4 * bq];
        float4 hv1 = *(const float4*)&h[(k + 1) * 32 + 4 * bq];
        float4 hv2 = *(const float4*)&h[(k + 2) * 32 + 4 * bq];
        float4 hv3 = *(const float4*)&h[(k + 3) * 32 + 4 * bq];
        #pragma unroll
        for (int r = 0; r < NR; r++){
            float4 w = *(const float4*)&wsm0[r * HID + k];
            acc[r][0] += w.x * hv0.x + w.y * hv1.x + w.z * hv2.x + w.w * hv3.x;
            acc[r][1] += w.x * hv0.y + w.y * hv1.y + w.z * hv2.y + w.w * hv3.y;
            acc[r][2] += w.x * hv0.z + w.y * hv1.z + w.z * hv2.z + w.w * hv3.z;
            acc[r][3] += w.x * hv0.w + w.y * hv1.w + w.z * hv2.w + w.w * hv3.w;
        }
    }
    #pragma unroll
    for (int r = 0; r < NR; r++)
        *(float4*)&part0[(r * NSLC + ks) * PPAD + 4 * bq] =
            make_float4(acc[r][0], acc[r][1], acc[r][2], acc[r][3]);
}

// ------- persistent 2-layer GRU, layer-pipelined: ONE barrier per step --------
__global__ __launch_bounds__(512, 2) void k_gru(
        const float* __restrict__ gi0,
        const float* __restrict__ wih1, const float* __restrict__ whh0,
        const float* __restrict__ whh1,
        const float* __restrict__ bih1, const float* __restrict__ bhh0,
        const float* __restrict__ bhh1,
        float* __restrict__ h0a, float* __restrict__ h0b,
        float* __restrict__ h1a, float* __restrict__ h1b,
        float* __restrict__ out, int* bar){
    __shared__ float wsm[18 * HID];            // rows 0-5: whh0, 6-11: wih1, 12-17: whh1
    __shared__ float part[18 * NSLC * PPAD];   // [row][ks][b(+pad)]
    __shared__ float ghl[18 * 32];
    __shared__ float outst[SEQ * 64];          // [step][bb*2+l] staged out2

    int tid = threadIdx.x;
    int i0 = blockIdx.x * 2;

    #pragma unroll
    for (int r = 0; r < 6; r++){
        int j = (r >> 1) * HID + i0 + (r & 1);
        for (int k = tid; k < HID; k += 512){
            wsm[r * HID + k]        = whh0[(size_t)j * HID + k];
            wsm[(6 + r) * HID + k]  = wih1[(size_t)j * HID + k];
            wsm[(12 + r) * HID + k] = whh1[(size_t)j * HID + k];
        }
    }
    __syncthreads();

    int t8  = tid & 255;
    int bq  = t8 & 7;                 // batch quad: batches 4bq..4bq+3
    int ks  = (t8 >> 3) & (NSLC - 1); // k-slice
    int rh  = t8 >> 7;                // row half within group
    int l   = (tid >> 5) & 1, bb = tid & 31;   // gate-thread coords (tid<64)
    int i   = i0 + l;
    float hs0 = 0.f, hs1 = 0.f;       // registered h state for own unit (tid<64)

    for (int p = 0; p <= SEQ; p++){
        const float* h0r = (p & 1) ? h0a : h0b;   // h0(p-1)  (also = out1(p-1))
        float*       h0w = (p & 1) ? h0b : h0a;   // h0(p)
        const float* h1r = (p & 1) ? h1b : h1a;   // h1(p-2)
        float*       h1w = (p & 1) ? h1a : h1b;   // h1(p-1)

        // prefetch this phase's gi gate inputs (independent of h) early
        float giR = 0.f, giZ = 0.f, giN = 0.f;
        if (tid < 64 && p < SEQ){
            const float* gi = gi0 + (size_t)(p * BATCH + bb) * G3;
            giR = gi[i]; giZ = gi[HID + i]; giN = gi[2 * HID + i];
        }

        if (tid < 256) gemv_part<6>(h0r, wsm + (rh * 6) * HID,
                                    part + (rh * 6) * NSLC * PPAD, bq, ks);
        else           gemv_part<3>(h1r, wsm + (12 + rh * 3) * HID,
                                    part + (12 + rh * 3) * NSLC * PPAD, bq, ks);
        __syncthreads();

        // stage-2 reduce over NSLC slices -> ghl[row][b]
        for (int o = tid; o < 18 * 32; o += 512){
            int row = o >> 5, b2 = o & 31;
            float sum = 0.f;
            #pragma unroll
            for (int q = 0; q < NSLC; q++) sum += part[(row * NSLC + q) * PPAD + b2];
            ghl[row * 32 + b2] = sum;
        }
        __syncthreads();

        if (tid < 64){
            if (p < SEQ){   // layer0 step p
                float ghr = ghl[(0 + l) * 32 + bb] + bhh0[i];
                float ghz = ghl[(2 + l) * 32 + bb] + bhh0[HID + i];
                float ghn = ghl[(4 + l) * 32 + bb] + bhh0[2 * HID + i];
                float rr = sigmoidf(giR + ghr);
                float zz = sigmoidf(giZ + ghz);
                float nn = tanhf(giN + rr * ghn);
                hs0 = (1.f - zz) * nn + zz * hs0;
                h0w[i * 32 + bb] = hs0;
            }
            if (p >= 1){    // layer1 step p-1
                float gir = ghl[(6 + l) * 32 + bb]  + bih1[i];
                float giz = ghl[(8 + l) * 32 + bb]  + bih1[HID + i];
                float gin = ghl[(10 + l) * 32 + bb] + bih1[2 * HID + i];
                float ghr = ghl[(12 + l) * 32 + bb] + bhh1[i];
                float ghz = ghl[(14 + l) * 32 + bb] + bhh1[HID + i];
                float ghn = ghl[(16 + l) * 32 + bb] + bhh1[2 * HID + i];
                float rr = sigmoidf(gir + ghr);
                float zz = sigmoidf(giz + ghz);
                float nn = tanhf(gin + rr * ghn);
                hs1 = (1.f - zz) * nn + zz * hs1;
                h1w[i * 32 + bb] = hs1;
                outst[(p - 1) * 64 + bb * 2 + l] = hs1;   // staged out2[p-1,b,i]
            }
        }
        if (p < SEQ) grid_barrier(bar, p + 1);
    }

    __syncthreads();
    // coalesced out2 write: 480 float2 stores (this block owns cols i0,i0+1)
    for (int o = tid; o < SEQ * 32; o += 512){
        int q = o >> 5, b2 = o & 31;
        float2 v = *(float2*)&outst[q * 64 + b2 * 2];
        *(float2*)&out[(size_t)(q * BATCH + b2) * HID + i0] = v;
    }
    // hn from registered state: h0(14), h1(14)
    if (tid < 64){
        out[SEQ * BATCH * HID + (size_t)bb * HID + i] = hs0;
        out[SEQ * BATCH * HID + BATCH * HID + (size_t)bb * HID + i] = hs1;
    }
}

extern "C" void kernel_launch(void* const* d_in, const int* in_sizes, int n_in,
                              void* d_out, int out_size, void* d_ws, size_t ws_size,
                              hipStream_t stream){
    (void)in_sizes; (void)n_in; (void)out_size; (void)ws_size;
    const float* x    = (const float*)d_in[0];
    const int*   ei   = (const int*)d_in[1];
    const float* W1   = (const float*)d_in[2];
    const float* b1   = (const float*)d_in[3];
    const float* W2   = (const float*)d_in[4];
    const float* b2   = (const float*)d_in[5];
    const float* wih0 = (const float*)d_in[6];
    const float* whh0 = (const float*)d_in[7];
    const float* bih0 = (const float*)d_in[8];
    const float* bhh0 = (const float*)d_in[9];
    const float* wih1 = (const float*)d_in[10];
    const float* whh1 = (const float*)d_in[11];
    const float* bih1 = (const float*)d_in[12];
    const float* bhh1 = (const float*)d_in[13];
    float* out = (float*)d_out;

    char* w = (char*)d_ws;
    auto alloc = [&](size_t bytes) -> char* {
        char* p = w; w += (bytes + 255) & ~(size_t)255; return p;
    };
    float* dinv   = (float*)alloc(NNODES * 4);
    int*   counts = (int*)  alloc(NNODES * 4);
    int*   offs   = (int*)  alloc((NNODES + 8) * 4);
    int*   fill   = (int*)  alloc(NNODES * 4);
    int*   csr    = (int*)  alloc(NEDGES * 4);
    int*   bar    = (int*)  alloc(BAR_INTS * 4);
    float* h0a    = (float*)alloc(HID * BATCH * 4);
    float* h0b    = (float*)alloc(HID * BATCH * 4);
    float* h1a    = (float*)alloc(HID * BATCH * 4);
    float* h1b    = (float*)alloc(HID * BATCH * 4);
    float* h1t    = (float*)alloc((size_t)SEQ * NNODES * BATCH * 2 * 4);  // [s][n][b][c]
    float* h2t    = (float*)alloc((size_t)SEQ * NNODES * BATCH * 4);      // [s][n][b]
    float* gbuf   = (float*)alloc((size_t)SEQ * BATCH * NNODES * 4);      // [s*32+b][n]
    float* gi0    = (float*)alloc((size_t)SEQ * BATCH * G3 * 4);
    // split-K partials (9 * 480 * 1536 * 4 = 26.5 MB) alias the h1t+h2t
    // region (19.2 MB + 9.6 MB contiguous): h1t is dead after k_agg1, h2t
    // after k_agg2 -- both before k_gemm runs.
    float* part   = h1t;

    k_init <<<64, 256, 0, stream>>>(counts, fill, bar, h0a, h0b, h1a, h1b);
    k_count<<<(NEDGES + 255) / 256, 256, 0, stream>>>(ei, counts);
    k_dinv <<<(NNODES + 255) / 256, 256, 0, stream>>>(counts, dinv);
    k_scan <<<1, 1024, 0, stream>>>(counts, offs);
    k_fill <<<(NEDGES + 255) / 256, 256, 0, stream>>>(ei, offs, fill, csr);

    dim3 gtile(NT64, SEQ);
    k_conv1<<<gtile, 256, 0, stream>>>(x, W1, dinv, h1t);
    k_agg1 <<<gtile, 256, 0, stream>>>(h1t, offs, csr, dinv, b1, W2, h2t);
    k_agg2 <<<gtile, 256, 0, stream>>>(h2t, offs, csr, dinv, b2, gbuf);

    k_gemm<<<dim3(G3 / 64, 8, KSPLIT), 256, 0, stream>>>(gbuf, wih0, part);
    k_gred<<<(MROWS * G3) / 256, 256, 0, stream>>>(part, bih0, gi0);

    k_gru<<<GRU_BLOCKS, 512, 0, stream>>>(gi0, wih1, whh0, whh1, bih1, bhh0, bhh1,
                                          h0a, h0b, h1a, h1b, out, bar);
}